// Round 6
// baseline (158.794 us; speedup 1.0000x reference)
//
#include <hip/hip_runtime.h>
#include <math.h>

#define B_DIM 128
#define N_DIM 512
#define D_DIM 512
#define H_DIM 256
#define K_SEL 8

typedef _Float16 half8 __attribute__((ext_vector_type(8)));
typedef float    f32x4 __attribute__((ext_vector_type(4)));

__device__ __forceinline__ void gload_lds16(const void* g, void* l) {
    __builtin_amdgcn_global_load_lds((const __attribute__((address_space(1))) void*)g,
                                     (__attribute__((address_space(3))) void*)l, 16, 0, 0);
}

// ---------------- Kernel 0: prep W1 -> transposed fp16 2-way split (l scaled by 2048) ----
// x = h + l'/2048 + eps, |eps| <= 2^-22|x|. Scaling keeps l' in fp16 normal range
// (raw residuals ~2^-11|x| would be fp16 subnormals -> MFMA flush risk).
__global__ __launch_bounds__(256) void prep_w1_kernel(
    const float* __restrict__ W1,
    _Float16* __restrict__ w1t_h,
    _Float16* __restrict__ w1t_l)
{
    const int c = blockIdx.x;      // 256 cols
    const int t = threadIdx.x;     // 256 threads over k
    #pragma unroll
    for (int kk = 0; kk < D_DIM; kk += 256) {
        int k = kk + t;
        float x = W1[(size_t)k * H_DIM + c];
        _Float16 h = (_Float16)x;
        float r = x - (float)h;
        w1t_h[(size_t)c * D_DIM + k] = h;
        w1t_l[(size_t)c * D_DIM + k] = (_Float16)(r * 2048.0f);
    }
}

// ---------------- Kernel 1: fp16x2-split MFMA scorer, 2 WGs/CU ----------------
// Grid: 1024 WGs x 256 threads. WG = 64 rows x 256 cols. 4 waves (1M x 4N), wave 64x64.
// 3 products per frag-pair: acc += ah*bh ; acc2 += ah*bl' + al'*bh ; z = acc + acc2/2048.
// LDS exactly 80 KB -> 2 resident WGs/CU (independent barriers overlap each other's stalls).
__global__ __launch_bounds__(256, 2) void fused_scorer_mfma(
    const float* __restrict__ X,           // (65536, 512)
    const _Float16* __restrict__ w1t_h,    // (256, 512) [col][k]
    const _Float16* __restrict__ w1t_l,
    const float* __restrict__ b1,          // (256)
    const float* __restrict__ W2,          // (256)
    const float* __restrict__ b2p,         // scalar
    const float* __restrict__ base_logits, // (512)
    float* __restrict__ logits)            // (65536)
{
    // A chunk = kc*64 + row (kc 0..3 of 8k, row 0..63), stored at chunk ^ (kc<<1)
    // B chunk = kc*256 + col, linear (gload_lds dest must be linear in tid)
    __shared__ half8 Ah[2][256], Al[2][256];    // 16 KB
    __shared__ half8 Bh[2][1024], Bl[2][1024];  // 64 KB

    const int tid  = threadIdx.x;
    const int lane = tid & 63;
    const int wave = tid >> 6;           // 0..3
    const int wn   = wave << 6;          // 0,64,128,192
    const int l15  = lane & 15;
    const int lg   = lane >> 4;          // 0..3
    const int row0 = blockIdx.x * 64;

    // A staging map: thread t -> row t>>2, k-chunk t&3 (8 consecutive k = 32 B)
    const int rowA = tid >> 2, kcA = tid & 3;
    const float* xp = X + (size_t)(row0 + rowA) * D_DIM + kcA * 8;
    const int achunk_sw = (kcA * 64 + rowA) ^ (kcA << 1);

    f32x4 acc[4][4], acc2[4][4];
    #pragma unroll
    for (int mi = 0; mi < 4; ++mi)
        #pragma unroll
        for (int nj = 0; nj < 4; ++nj) {
            acc[mi][nj]  = (f32x4){0.f, 0.f, 0.f, 0.f};
            acc2[mi][nj] = (f32x4){0.f, 0.f, 0.f, 0.f};
        }

    float b1v[4], w2v[4];
    #pragma unroll
    for (int nj = 0; nj < 4; ++nj) {
        int col = wn + nj * 16 + l15;
        b1v[nj] = b1[col];
        w2v[nj] = W2[col];
    }

    auto split_write = [&](int buf, float4 va, float4 vb) {
        float e[8] = {va.x, va.y, va.z, va.w, vb.x, vb.y, vb.z, vb.w};
        half8 hh, ll;
        #pragma unroll
        for (int j = 0; j < 8; ++j) {
            _Float16 h = (_Float16)e[j];
            float r = e[j] - (float)h;
            hh[j] = h;
            ll[j] = (_Float16)(r * 2048.0f);
        }
        Ah[buf][achunk_sw] = hh;
        Al[buf][achunk_sw] = ll;
    };
    auto stage_b = [&](int buf, int kc0) {
        const _Float16* sh = w1t_h + (size_t)tid * D_DIM + kc0;  // col = tid
        const _Float16* sl = w1t_l + (size_t)tid * D_DIM + kc0;
        #pragma unroll
        for (int q = 0; q < 4; ++q) {
            gload_lds16(sh + q * 8, &Bh[buf][q * 256 + tid]);
            gload_lds16(sl + q * 8, &Bl[buf][q * 256 + tid]);
        }
    };

    // ---- prologue ----
    float4 xa = *reinterpret_cast<const float4*>(xp);
    float4 xb = *reinterpret_cast<const float4*>(xp + 4);
    stage_b(0, 0);
    split_write(0, xa, xb);
    xa = *reinterpret_cast<const float4*>(xp + 32);
    xb = *reinterpret_cast<const float4*>(xp + 36);
    __syncthreads();

    for (int ks = 0; ks < 16; ++ks) {
        const int buf = ks & 1, nbuf = buf ^ 1;
        stage_b(nbuf, ((ks + 1) * 32) & 511);        // DMA lands under MFMA block
        split_write(nbuf, xa, xb);
        const int k2 = ((ks + 2) * 32) & 511;
        xa = *reinterpret_cast<const float4*>(xp + k2);
        xb = *reinterpret_cast<const float4*>(xp + k2 + 4);

        half8 fah[4], fal[4], fbh[4], fbl[4];
        #pragma unroll
        for (int mi = 0; mi < 4; ++mi) {
            int ca = (lg * 64 + mi * 16 + l15) ^ (lg << 1);
            fah[mi] = Ah[buf][ca];
            fal[mi] = Al[buf][ca];
        }
        #pragma unroll
        for (int nj = 0; nj < 4; ++nj) {
            int cb = lg * 256 + wn + nj * 16 + l15;
            fbh[nj] = Bh[buf][cb];
            fbl[nj] = Bl[buf][cb];
        }
        // 48 MFMAs: hh -> acc ; h*l' + l'*h -> acc2 (scaled by 2048)
        #pragma unroll
        for (int mi = 0; mi < 4; ++mi)
            #pragma unroll
            for (int nj = 0; nj < 4; ++nj) {
                acc[mi][nj]  = __builtin_amdgcn_mfma_f32_16x16x32_f16(fah[mi], fbh[nj], acc[mi][nj],  0, 0, 0);
                acc2[mi][nj] = __builtin_amdgcn_mfma_f32_16x16x32_f16(fah[mi], fbl[nj], acc2[mi][nj], 0, 0, 0);
                acc2[mi][nj] = __builtin_amdgcn_mfma_f32_16x16x32_f16(fal[mi], fbh[nj], acc2[mi][nj], 0, 0, 0);
            }
        __syncthreads();
    }

    // ---- epilogue: z = acc + acc2/2048 + b1 ; exact GELU ; dot W2 ; reduce ----
    float* red = reinterpret_cast<float*>(&Ah[0][0]);  // A buffers dead; 4*64 floats
    float part[4][4];
    #pragma unroll
    for (int mi = 0; mi < 4; ++mi)
        #pragma unroll
        for (int r = 0; r < 4; ++r)
            part[mi][r] = 0.f;
    #pragma unroll
    for (int mi = 0; mi < 4; ++mi)
        #pragma unroll
        for (int nj = 0; nj < 4; ++nj)
            #pragma unroll
            for (int r = 0; r < 4; ++r) {
                float z = acc[mi][nj][r] + acc2[mi][nj][r] * (1.0f / 2048.0f) + b1v[nj];
                float g = 0.5f * z * (1.0f + erff(z * 0.70710678118654752440f));
                part[mi][r] = fmaf(g, w2v[nj], part[mi][r]);
            }
    #pragma unroll
    for (int mi = 0; mi < 4; ++mi)
        #pragma unroll
        for (int r = 0; r < 4; ++r) {
            float v = part[mi][r];
            v += __shfl_xor(v, 1, 16);
            v += __shfl_xor(v, 2, 16);
            v += __shfl_xor(v, 4, 16);
            v += __shfl_xor(v, 8, 16);
            if (l15 == 0)
                red[wave * 64 + mi * 16 + lg * 4 + r] = v;
        }
    __syncthreads();
    if (tid < 64) {
        float s = red[tid] + red[64 + tid] + red[128 + tid] + red[192 + tid];
        int grow = row0 + tid;
        logits[grow] = s + b2p[0] + base_logits[grow & (N_DIM - 1)];
    }
}

// ---------------- Kernel 2: softmax + top-8 + mask/importance/indices ----------------
__global__ __launch_bounds__(256) void softmax_topk_kernel(
    const float* __restrict__ logits,
    float* __restrict__ out_mask,
    float* __restrict__ out_importance,
    float* __restrict__ out_indices)
{
    const int b = blockIdx.x;
    const int tid = threadIdx.x;
    __shared__ float probs[N_DIM];
    __shared__ float redf[4];
    __shared__ int   redi[4];
    __shared__ int   sel_idx[K_SEL];

    float l0 = logits[b * N_DIM + tid];
    float l1 = logits[b * N_DIM + tid + 256];

    float m = fmaxf(l0, l1);
    #pragma unroll
    for (int s = 32; s >= 1; s >>= 1) m = fmaxf(m, __shfl_xor(m, s, 64));
    if ((tid & 63) == 0) redf[tid >> 6] = m;
    __syncthreads();
    float gm = fmaxf(fmaxf(redf[0], redf[1]), fmaxf(redf[2], redf[3]));
    __syncthreads();

    float e0 = expf(l0 - gm), e1 = expf(l1 - gm);
    float ssum = e0 + e1;
    #pragma unroll
    for (int s = 32; s >= 1; s >>= 1) ssum += __shfl_xor(ssum, s, 64);
    if ((tid & 63) == 0) redf[tid >> 6] = ssum;
    __syncthreads();
    float denom = redf[0] + redf[1] + redf[2] + redf[3];
    float p0 = e0 / denom, p1 = e1 / denom;
    probs[tid] = p0;
    probs[tid + 256] = p1;
    out_importance[b * N_DIM + tid] = p0;
    out_importance[b * N_DIM + tid + 256] = p1;
    __syncthreads();

    for (int it = 0; it < K_SEL; ++it) {
        float v0 = probs[tid]; int i0 = tid;
        float v1 = probs[tid + 256];
        if (v1 > v0) { v0 = v1; i0 = tid + 256; }
        #pragma unroll
        for (int s = 32; s >= 1; s >>= 1) {
            float ov = __shfl_xor(v0, s, 64);
            int   oi = __shfl_xor(i0, s, 64);
            if (ov > v0 || (ov == v0 && oi < i0)) { v0 = ov; i0 = oi; }
        }
        if ((tid & 63) == 0) { redf[tid >> 6] = v0; redi[tid >> 6] = i0; }
        __syncthreads();
        if (tid == 0) {
            float bv = redf[0]; int bi = redi[0];
            for (int w = 1; w < 4; ++w)
                if (redf[w] > bv || (redf[w] == bv && redi[w] < bi)) { bv = redf[w]; bi = redi[w]; }
            sel_idx[it] = bi;
            probs[bi] = -1.0f;
        }
        __syncthreads();
    }

    float mk0 = 0.f, mk1 = 0.f;
    #pragma unroll
    for (int i = 0; i < K_SEL; ++i) {
        if (sel_idx[i] == tid)       mk0 = 1.f;
        if (sel_idx[i] == tid + 256) mk1 = 1.f;
    }
    out_mask[b * N_DIM + tid] = mk0;
    out_mask[b * N_DIM + tid + 256] = mk1;

    if (tid < K_SEL) out_indices[b * K_SEL + tid] = (float)sel_idx[tid];
}

// ---------------- Kernel 3: gather selected rows (overwrites scratch last) ----------
__global__ __launch_bounds__(256) void gather_kernel(
    const float* __restrict__ X,
    const float* __restrict__ out_indices,
    float* __restrict__ out_selected)
{
    const int b = blockIdx.x;
    const int tid = threadIdx.x;
    __shared__ int sel[K_SEL];
    if (tid < K_SEL) sel[tid] = (int)out_indices[b * K_SEL + tid];
    __syncthreads();
    #pragma unroll
    for (int i = 0; i < 4; ++i) {
        int f = tid + 256 * i;
        int ki = f >> 7;
        int c4 = f & 127;
        float4 v = reinterpret_cast<const float4*>(
            X + ((size_t)b * N_DIM + sel[ki]) * D_DIM)[c4];
        reinterpret_cast<float4*>(
            out_selected + ((size_t)b * K_SEL + ki) * D_DIM)[c4] = v;
    }
}

extern "C" void kernel_launch(void* const* d_in, const int* in_sizes, int n_in,
                              void* d_out, int out_size, void* d_ws, size_t ws_size,
                              hipStream_t stream) {
    const float* X           = (const float*)d_in[0];
    const float* W1          = (const float*)d_in[1];
    const float* b1          = (const float*)d_in[2];
    const float* W2          = (const float*)d_in[3];
    const float* b2          = (const float*)d_in[4];
    const float* base_logits = (const float*)d_in[5];

    float* out            = (float*)d_out;
    float* out_selected   = out;                                  // 128*8*512 = 524288
    float* out_mask       = out_selected + B_DIM * K_SEL * D_DIM; // 128*512
    float* out_importance = out_mask + B_DIM * N_DIM;             // 128*512
    float* out_indices    = out_importance + B_DIM * N_DIM;       // 128*8

    // Scratch inside out_selected's region (gather overwrites it last):
    float*    logits = out_selected;                         // [0, 65536) f32
    _Float16* w1t_h  = (_Float16*)(out_selected + 65536);    // 131072 halfs
    _Float16* w1t_l  = (_Float16*)(out_selected + 131072);   // 131072 halfs

    hipLaunchKernelGGL(prep_w1_kernel, dim3(H_DIM), dim3(256), 0, stream,
                       W1, w1t_h, w1t_l);
    hipLaunchKernelGGL(fused_scorer_mfma, dim3((B_DIM * N_DIM) / 64), dim3(256), 0, stream,
                       X, w1t_h, w1t_l, b1, W2, b2, base_logits, logits);
    hipLaunchKernelGGL(softmax_topk_kernel, dim3(B_DIM), dim3(256), 0, stream,
                       logits, out_mask, out_importance, out_indices);
    hipLaunchKernelGGL(gather_kernel, dim3(B_DIM), dim3(256), 0, stream,
                       X, out_indices, out_selected);
}

// Round 7
// 136.780 us; speedup vs baseline: 1.1609x; 1.1609x over previous
//
#include <hip/hip_runtime.h>
#include <math.h>

#define B_DIM 128
#define N_DIM 512
#define D_DIM 512
#define H_DIM 256
#define K_SEL 8

typedef _Float16 half8 __attribute__((ext_vector_type(8)));
typedef float    f32x4 __attribute__((ext_vector_type(4)));

__device__ __forceinline__ void gload_lds16(const void* g, void* l) {
    __builtin_amdgcn_global_load_lds((const __attribute__((address_space(1))) void*)g,
                                     (__attribute__((address_space(3))) void*)l, 16, 0, 0);
}

// ---------------- Kernel 0: prep W1 -> transposed fp16 2-way split (l scaled by 2048) ----
// x = h + l'/2048 + eps, |eps| <= 2^-22|x|. Scaling keeps l' in fp16 normal range.
__global__ __launch_bounds__(256) void prep_w1_kernel(
    const float* __restrict__ W1,
    _Float16* __restrict__ w1t_h,
    _Float16* __restrict__ w1t_l)
{
    const int c = blockIdx.x;      // 256 cols
    const int t = threadIdx.x;     // 256 threads over k
    #pragma unroll
    for (int kk = 0; kk < D_DIM; kk += 256) {
        int k = kk + t;
        float x = W1[(size_t)k * H_DIM + c];
        _Float16 h = (_Float16)x;
        float r = x - (float)h;
        w1t_h[(size_t)c * D_DIM + k] = h;
        w1t_l[(size_t)c * D_DIM + k] = (_Float16)(r * 2048.0f);
    }
}

// ---------------- Kernel 1: fp16x2-split MFMA scorer, BM=256 (VMEM-minimized) ----------
// Grid: 256 WGs x 512 threads (exactly 1 WG/CU, single batch).
// WG = 256 rows x 256 cols; 8 waves 2Mx4N; per-wave 128x64 = 8x4 frags.
// Total VMEM: A 134 MB + B 134 MB (vs 646 MB in round 6) — staging-throughput-bound.
// acc2 folded per-fragment (4 VGPR temp) to stay under 256 VGPR for 2 waves/SIMD.
__global__ __launch_bounds__(512, 2) void fused_scorer_mfma(
    const float* __restrict__ X,           // (65536, 512)
    const _Float16* __restrict__ w1t_h,    // (256, 512) [col][k]
    const _Float16* __restrict__ w1t_l,
    const float* __restrict__ b1,          // (256)
    const float* __restrict__ W2,          // (256)
    const float* __restrict__ b2p,         // scalar
    const float* __restrict__ base_logits, // (512)
    float* __restrict__ logits)            // (65536)
{
    // chunk16 = half8; chunk index = kc*256 + row/col (kc 0..3 of 8 k each)
    __shared__ half8 Ah[2][1024], Al[2][1024];   // 64 KB
    __shared__ half8 Bh[2][1024], Bl[2][1024];   // 64 KB

    const int tid  = threadIdx.x;
    const int lane = tid & 63;
    const int wave = tid >> 6;            // 0..7
    const int wm   = (wave >> 2) << 7;    // 0 / 128
    const int wn   = (wave & 3) << 6;     // 0,64,128,192
    const int l15  = lane & 15;
    const int lg   = lane >> 4;           // 0..3
    const int row0 = blockIdx.x * 256;

    // staging maps (both A and B): thread t -> row/col = t&255, kc pair = (t>>8)*2
    const int rc  = tid & 255;
    const int kc0 = (tid >> 8) * 2;       // 0 or 2 (wave-uniform)
    const float*    xp  = X + (size_t)(row0 + rc) * D_DIM + kc0 * 8;
    const _Float16* bph = w1t_h + (size_t)rc * D_DIM + kc0 * 8;
    const _Float16* bpl = w1t_l + (size_t)rc * D_DIM + kc0 * 8;

    f32x4 acc[8][4];
    #pragma unroll
    for (int mi = 0; mi < 8; ++mi)
        #pragma unroll
        for (int nj = 0; nj < 4; ++nj)
            acc[mi][nj] = (f32x4){0.f, 0.f, 0.f, 0.f};

    float b1v[4], w2v[4];
    #pragma unroll
    for (int nj = 0; nj < 4; ++nj) {
        int col = wn + nj * 16 + l15;
        b1v[nj] = b1[col];
        w2v[nj] = W2[col];
    }

    // split 16 floats (2 adjacent k-chunks) -> h/l' half8, write chunks (kc0,kc0+1)*256+rc
    auto split_write = [&](int buf, const float4* v) {
        #pragma unroll
        for (int q = 0; q < 2; ++q) {
            float e[8] = {v[2*q].x, v[2*q].y, v[2*q].z, v[2*q].w,
                          v[2*q+1].x, v[2*q+1].y, v[2*q+1].z, v[2*q+1].w};
            half8 hh, ll;
            #pragma unroll
            for (int j = 0; j < 8; ++j) {
                _Float16 h = (_Float16)e[j];
                float r = e[j] - (float)h;
                hh[j] = h;
                ll[j] = (_Float16)(r * 2048.0f);
            }
            Ah[buf][(kc0 + q) * 256 + rc] = hh;
            Al[buf][(kc0 + q) * 256 + rc] = ll;
        }
    };
    auto stage_b = [&](int buf, int kb) {
        #pragma unroll
        for (int q = 0; q < 2; ++q) {
            gload_lds16(bph + kb + q * 8, &Bh[buf][(kc0 + q) * 256 + rc]);
            gload_lds16(bpl + kb + q * 8, &Bl[buf][(kc0 + q) * 256 + rc]);
        }
    };

    // ---- prologue: stage k-step 0; prefetch A(1) ----
    float4 xv[4];
    #pragma unroll
    for (int i = 0; i < 4; ++i) xv[i] = reinterpret_cast<const float4*>(xp)[i];
    stage_b(0, 0);
    split_write(0, xv);
    #pragma unroll
    for (int i = 0; i < 4; ++i) xv[i] = reinterpret_cast<const float4*>(xp + 32)[i];
    __syncthreads();

    for (int ks = 0; ks < 16; ++ks) {
        const int buf = ks & 1, nbuf = buf ^ 1;
        stage_b(nbuf, ((ks + 1) * 32) & 511);        // DMA lands under MFMA block
        split_write(nbuf, xv);
        const int k2 = ((ks + 2) * 32) & 511;
        #pragma unroll
        for (int i = 0; i < 4; ++i) xv[i] = reinterpret_cast<const float4*>(xp + k2)[i];

        half8 fbh[4], fbl[4];
        #pragma unroll
        for (int nj = 0; nj < 4; ++nj) {
            int cb = lg * 256 + wn + nj * 16 + l15;
            fbh[nj] = Bh[buf][cb];
            fbl[nj] = Bl[buf][cb];
        }
        #pragma unroll
        for (int mi = 0; mi < 8; ++mi) {
            int ca = lg * 256 + wm + mi * 16 + l15;
            half8 fah = Ah[buf][ca];
            half8 fal = Al[buf][ca];
            #pragma unroll
            for (int nj = 0; nj < 4; ++nj) {
                acc[mi][nj] = __builtin_amdgcn_mfma_f32_16x16x32_f16(fah, fbh[nj], acc[mi][nj], 0, 0, 0);
                f32x4 t = __builtin_amdgcn_mfma_f32_16x16x32_f16(fah, fbl[nj], (f32x4){0.f,0.f,0.f,0.f}, 0, 0, 0);
                t = __builtin_amdgcn_mfma_f32_16x16x32_f16(fal, fbh[nj], t, 0, 0, 0);
                acc[mi][nj] += t * (1.0f / 2048.0f);
            }
        }
        __syncthreads();
    }

    // ---- epilogue: z = acc + b1 ; exact GELU ; dot W2 ; reduce 16 lanes + 4 N-waves ----
    float* red = reinterpret_cast<float*>(&Ah[0][0]);  // dead A buffer; 4*256 floats
    float part[8][4];
    #pragma unroll
    for (int mi = 0; mi < 8; ++mi)
        #pragma unroll
        for (int r = 0; r < 4; ++r)
            part[mi][r] = 0.f;
    #pragma unroll
    for (int mi = 0; mi < 8; ++mi)
        #pragma unroll
        for (int nj = 0; nj < 4; ++nj)
            #pragma unroll
            for (int r = 0; r < 4; ++r) {
                float z = acc[mi][nj][r] + b1v[nj];
                float g = 0.5f * z * (1.0f + erff(z * 0.70710678118654752440f));
                part[mi][r] = fmaf(g, w2v[nj], part[mi][r]);
            }
    __syncthreads();   // A buffer fully dead before reuse as red
    #pragma unroll
    for (int mi = 0; mi < 8; ++mi)
        #pragma unroll
        for (int r = 0; r < 4; ++r) {
            float v = part[mi][r];
            v += __shfl_xor(v, 1, 16);
            v += __shfl_xor(v, 2, 16);
            v += __shfl_xor(v, 4, 16);
            v += __shfl_xor(v, 8, 16);
            if (l15 == 0)
                red[(wave & 3) * 256 + wm + mi * 16 + lg * 4 + r] = v;
        }
    __syncthreads();
    if (tid < 256) {
        float s = red[tid] + red[256 + tid] + red[512 + tid] + red[768 + tid];
        int grow = row0 + tid;
        logits[grow] = s + b2p[0] + base_logits[grow & (N_DIM - 1)];
    }
}

// ---------------- Kernel 2: softmax + top-8 + mask/importance/indices ----------------
__global__ __launch_bounds__(256) void softmax_topk_kernel(
    const float* __restrict__ logits,
    float* __restrict__ out_mask,
    float* __restrict__ out_importance,
    float* __restrict__ out_indices)
{
    const int b = blockIdx.x;
    const int tid = threadIdx.x;
    __shared__ float probs[N_DIM];
    __shared__ float redf[4];
    __shared__ int   redi[4];
    __shared__ int   sel_idx[K_SEL];

    float l0 = logits[b * N_DIM + tid];
    float l1 = logits[b * N_DIM + tid + 256];

    float m = fmaxf(l0, l1);
    #pragma unroll
    for (int s = 32; s >= 1; s >>= 1) m = fmaxf(m, __shfl_xor(m, s, 64));
    if ((tid & 63) == 0) redf[tid >> 6] = m;
    __syncthreads();
    float gm = fmaxf(fmaxf(redf[0], redf[1]), fmaxf(redf[2], redf[3]));
    __syncthreads();

    float e0 = expf(l0 - gm), e1 = expf(l1 - gm);
    float ssum = e0 + e1;
    #pragma unroll
    for (int s = 32; s >= 1; s >>= 1) ssum += __shfl_xor(ssum, s, 64);
    if ((tid & 63) == 0) redf[tid >> 6] = ssum;
    __syncthreads();
    float denom = redf[0] + redf[1] + redf[2] + redf[3];
    float p0 = e0 / denom, p1 = e1 / denom;
    probs[tid] = p0;
    probs[tid + 256] = p1;
    out_importance[b * N_DIM + tid] = p0;
    out_importance[b * N_DIM + tid + 256] = p1;
    __syncthreads();

    for (int it = 0; it < K_SEL; ++it) {
        float v0 = probs[tid]; int i0 = tid;
        float v1 = probs[tid + 256];
        if (v1 > v0) { v0 = v1; i0 = tid + 256; }
        #pragma unroll
        for (int s = 32; s >= 1; s >>= 1) {
            float ov = __shfl_xor(v0, s, 64);
            int   oi = __shfl_xor(i0, s, 64);
            if (ov > v0 || (ov == v0 && oi < i0)) { v0 = ov; i0 = oi; }
        }
        if ((tid & 63) == 0) { redf[tid >> 6] = v0; redi[tid >> 6] = i0; }
        __syncthreads();
        if (tid == 0) {
            float bv = redf[0]; int bi = redi[0];
            for (int w = 1; w < 4; ++w)
                if (redf[w] > bv || (redf[w] == bv && redi[w] < bi)) { bv = redf[w]; bi = redi[w]; }
            sel_idx[it] = bi;
            probs[bi] = -1.0f;
        }
        __syncthreads();
    }

    float mk0 = 0.f, mk1 = 0.f;
    #pragma unroll
    for (int i = 0; i < K_SEL; ++i) {
        if (sel_idx[i] == tid)       mk0 = 1.f;
        if (sel_idx[i] == tid + 256) mk1 = 1.f;
    }
    out_mask[b * N_DIM + tid] = mk0;
    out_mask[b * N_DIM + tid + 256] = mk1;

    if (tid < K_SEL) out_indices[b * K_SEL + tid] = (float)sel_idx[tid];
}

// ---------------- Kernel 3: gather selected rows (overwrites scratch last) ----------
__global__ __launch_bounds__(256) void gather_kernel(
    const float* __restrict__ X,
    const float* __restrict__ out_indices,
    float* __restrict__ out_selected)
{
    const int b = blockIdx.x;
    const int tid = threadIdx.x;
    __shared__ int sel[K_SEL];
    if (tid < K_SEL) sel[tid] = (int)out_indices[b * K_SEL + tid];
    __syncthreads();
    #pragma unroll
    for (int i = 0; i < 4; ++i) {
        int f = tid + 256 * i;
        int ki = f >> 7;
        int c4 = f & 127;
        float4 v = reinterpret_cast<const float4*>(
            X + ((size_t)b * N_DIM + sel[ki]) * D_DIM)[c4];
        reinterpret_cast<float4*>(
            out_selected + ((size_t)b * K_SEL + ki) * D_DIM)[c4] = v;
    }
}

extern "C" void kernel_launch(void* const* d_in, const int* in_sizes, int n_in,
                              void* d_out, int out_size, void* d_ws, size_t ws_size,
                              hipStream_t stream) {
    const float* X           = (const float*)d_in[0];
    const float* W1          = (const float*)d_in[1];
    const float* b1          = (const float*)d_in[2];
    const float* W2          = (const float*)d_in[3];
    const float* b2          = (const float*)d_in[4];
    const float* base_logits = (const float*)d_in[5];

    float* out            = (float*)d_out;
    float* out_selected   = out;                                  // 128*8*512 = 524288
    float* out_mask       = out_selected + B_DIM * K_SEL * D_DIM; // 128*512
    float* out_importance = out_mask + B_DIM * N_DIM;             // 128*512
    float* out_indices    = out_importance + B_DIM * N_DIM;       // 128*8

    // Scratch inside out_selected's region (gather overwrites it last):
    float*    logits = out_selected;                         // [0, 65536) f32
    _Float16* w1t_h  = (_Float16*)(out_selected + 65536);    // 131072 halfs
    _Float16* w1t_l  = (_Float16*)(out_selected + 131072);   // 131072 halfs

    hipLaunchKernelGGL(prep_w1_kernel, dim3(H_DIM), dim3(256), 0, stream,
                       W1, w1t_h, w1t_l);
    hipLaunchKernelGGL(fused_scorer_mfma, dim3((B_DIM * N_DIM) / 256), dim3(512), 0, stream,
                       X, w1t_h, w1t_l, b1, W2, b2, base_logits, logits);
    hipLaunchKernelGGL(softmax_topk_kernel, dim3(B_DIM), dim3(256), 0, stream,
                       logits, out_mask, out_importance, out_indices);
    hipLaunchKernelGGL(gather_kernel, dim3(B_DIM), dim3(256), 0, stream,
                       X, out_indices, out_selected);
}